// Round 3
// baseline (67.967 us; speedup 1.0000x reference)
//
#include <hip/hip_runtime.h>
#include <stdint.h>

// Problem constants (match reference)
#define NB   8
#define NC   256
#define NT   1024
#define NM   512
#define NNEG 100

// ---------------- Threefry-2x32-20 (JAX) ----------------
__device__ __forceinline__ unsigned rotl32(unsigned x, int d) {
  return (x << d) | (x >> (32 - d));
}

__device__ unsigned threefry_bits(unsigned i) {
  const unsigned half = 1048576u; // 2^20
  const bool lo = i < half;
  unsigned v0 = lo ? i : (i - half);
  unsigned v1 = lo ? (i + half) : i;
  const unsigned k0 = 0u, k1 = 42u;
  const unsigned k2 = k0 ^ k1 ^ 0x1BD11BDAu;
  v0 += k0; v1 += k1;
#define TF_R(r) { v0 += v1; v1 = rotl32(v1, r); v1 ^= v0; }
  TF_R(13) TF_R(15) TF_R(26) TF_R(6)
  v0 += k1; v1 += k2 + 1u;
  TF_R(17) TF_R(29) TF_R(16) TF_R(24)
  v0 += k2; v1 += k0 + 2u;
  TF_R(13) TF_R(15) TF_R(26) TF_R(6)
  v0 += k0; v1 += k1 + 3u;
  TF_R(17) TF_R(29) TF_R(16) TF_R(24)
  v0 += k1; v1 += k2 + 4u;
  TF_R(13) TF_R(15) TF_R(26) TF_R(6)
  v0 += k2; v1 += k0 + 5u;
#undef TF_R
  return lo ? v0 : v1;
}

// ---------------- Kernel 1: masked index extraction (1 block, 8 waves) ------
// Wave w handles batch row w; lane covers 16 consecutive timesteps.
// Shuffle-based exclusive scan; also writes inverse map pos[b][t] (-1 if not).
__global__ __launch_bounds__(512) void k_idx(const void* __restrict__ maskp,
                                             int* __restrict__ idxp,
                                             int* __restrict__ pos) {
  __shared__ int sflag;
  const int t = threadIdx.x;
  const int lane = t & 63, w = t >> 6;
  const unsigned char* mb = (const unsigned char*)maskp;

  // storage-width detection on the first 1024 elements (>=8KB in-bounds)
  if (w == 0) {
    int c1 = 0, c4 = 0, c8 = 0;
    for (int j = 0; j < 16; ++j) {
      int p = lane * 16 + j;
      c1 += (mb[p] != 0);
      c4 += (((const unsigned*)mb)[p] != 0u);
      c8 += (((const unsigned long long*)mb)[p] != 0ull);
    }
#pragma unroll
    for (int off = 32; off > 0; off >>= 1) {
      c1 += __shfl_xor(c1, off, 64);
      c4 += __shfl_xor(c4, off, 64);
      c8 += __shfl_xor(c8, off, 64);
    }
    if (lane == 0) sflag = (c4 == 512) ? 4 : ((c1 == 512) ? 1 : ((c8 == 512) ? 8 : 4));
  }
  __syncthreads();
  const int stride = sflag;
  const int b = w;

  unsigned fm = 0; int cnt = 0;
  for (int j = 0; j < 16; ++j) {
    int tt = lane * 16 + j;
    size_t e = (size_t)b * NT + tt;
    int f;
    if (stride == 1)      f = (mb[e] != 0);
    else if (stride == 4) f = (((const unsigned*)mb)[e] != 0u);
    else                  f = (((const unsigned long long*)mb)[e] != 0ull);
    fm |= ((unsigned)f) << j;
    cnt += f;
  }
  // exclusive prefix over lanes
  int pre = cnt;
#pragma unroll
  for (int off = 1; off < 64; off <<= 1) {
    int o = __shfl_up(pre, off, 64);
    if (lane >= off) pre += o;
  }
  int base = pre - cnt;
  for (int j = 0; j < 16; ++j) {
    int tt = lane * 16 + j;
    int masked = (fm >> j) & 1;
    pos[b * NT + tt] = masked ? base : -1;
    if (masked) { idxp[b * NM + base] = tt; base++; }
  }
}

// ---------------- Kernel 2a: compaction / transpose ----------------
// Per block: one [64c x 128t] slab of one matrix of one batch.
// Coalesced read along T -> LDS -> coalesced 256B row writes into [B,M,C].
__global__ __launch_bounds__(256) void k_compact(const float* __restrict__ ctx,
                                                 const float* __restrict__ feat,
                                                 const int* __restrict__ pos,
                                                 float* __restrict__ MC,
                                                 float* __restrict__ MF) {
  __shared__ float lds[64][129];
  const int tid = threadIdx.x;
  const int t0 = blockIdx.x * 128;
  const int c0 = blockIdx.y * 64;
  const int b = blockIdx.z >> 1, mat = blockIdx.z & 1;
  const float* src = (mat ? feat : ctx) + (size_t)b * NC * NT;
  float* dst = (mat ? MF : MC) + (size_t)b * NM * NC;

  const int c4 = tid >> 6;      // 0..3
  const int tl = tid & 63;      // lane along t (read) / along c (write)
  for (int ci = 0; ci < 16; ++ci) {
    int cc = c4 * 16 + ci;
#pragma unroll
    for (int tj = 0; tj < 2; ++tj) {
      int tt = tl + 64 * tj;
      lds[cc][tt] = src[(size_t)(c0 + cc) * NT + t0 + tt];
    }
  }
  __syncthreads();

  const int* posb = pos + b * NT + t0;
  const int tr = tid >> 6;      // 0..3
  for (int tt = tr; tt < 128; tt += 4) {
    int p = posb[tt];
    if (p >= 0) dst[(size_t)p * NC + c0 + tl] = lds[tl][tt];
  }
}

// ---------------- Kernel 2b: NT f32 GEMM on compacted operands -------------
// S[b][m][j] = sum_c MC[b][m][c] * MF[b][j][c]; 64x64 tile, 4x4 per thread,
// coalesced 16B staging loads + register prefetch of next K-slab.
__global__ __launch_bounds__(256) void k_gemm2(const float* __restrict__ MC,
                                               const float* __restrict__ MF,
                                               float* __restrict__ S) {
  __shared__ float At[16][68];
  __shared__ float Bt[16][68];
  const int tid = threadIdx.x;
  const int b = blockIdx.z, m0 = blockIdx.y * 64, j0 = blockIdx.x * 64;
  const float* Ab = MC + ((size_t)b * NM + m0) * NC;
  const float* Bb = MF + ((size_t)b * NM + j0) * NC;
  const int row = tid >> 2, q = tid & 3;   // staging: 64 rows x 4 float4
  const int ty = tid >> 4, tx = tid & 15;  // compute: 16x16 threads

  float acc[4][4];
#pragma unroll
  for (int i = 0; i < 4; ++i)
#pragma unroll
    for (int k = 0; k < 4; ++k) acc[i][k] = 0.f;

  float4 av = *(const float4*)(Ab + (size_t)row * NC + 4 * q);
  float4 bv = *(const float4*)(Bb + (size_t)row * NC + 4 * q);

  for (int c0 = 0; c0 < NC; c0 += 16) {
    At[4 * q + 0][row] = av.x; At[4 * q + 1][row] = av.y;
    At[4 * q + 2][row] = av.z; At[4 * q + 3][row] = av.w;
    Bt[4 * q + 0][row] = bv.x; Bt[4 * q + 1][row] = bv.y;
    Bt[4 * q + 2][row] = bv.z; Bt[4 * q + 3][row] = bv.w;
    __syncthreads();
    if (c0 + 16 < NC) {
      av = *(const float4*)(Ab + (size_t)row * NC + c0 + 16 + 4 * q);
      bv = *(const float4*)(Bb + (size_t)row * NC + c0 + 16 + 4 * q);
    }
#pragma unroll
    for (int cc = 0; cc < 16; ++cc) {
      float a0 = At[cc][ty * 4 + 0], a1 = At[cc][ty * 4 + 1];
      float a2 = At[cc][ty * 4 + 2], a3 = At[cc][ty * 4 + 3];
      float b0 = Bt[cc][tx * 4 + 0], b1 = Bt[cc][tx * 4 + 1];
      float b2 = Bt[cc][tx * 4 + 2], b3 = Bt[cc][tx * 4 + 3];
      acc[0][0] += a0 * b0; acc[0][1] += a0 * b1; acc[0][2] += a0 * b2; acc[0][3] += a0 * b3;
      acc[1][0] += a1 * b0; acc[1][1] += a1 * b1; acc[1][2] += a1 * b2; acc[1][3] += a1 * b3;
      acc[2][0] += a2 * b0; acc[2][1] += a2 * b1; acc[2][2] += a2 * b2; acc[2][3] += a2 * b3;
      acc[3][0] += a3 * b0; acc[3][1] += a3 * b1; acc[3][2] += a3 * b2; acc[3][3] += a3 * b3;
    }
    __syncthreads();
  }

#pragma unroll
  for (int i = 0; i < 4; ++i) {
    float4 v = make_float4(acc[i][0], acc[i][1], acc[i][2], acc[i][3]);
    *(float4*)&S[((size_t)b * NM + m0 + ty * 4 + i) * NM + j0 + tx * 4] = v;
  }
}

// ---------------- Kernel 3: histogram top-100 + parallel loss ----------------
__global__ __launch_bounds__(512) void k_loss(const float* __restrict__ S,
                                              float* __restrict__ pl,
                                              float* __restrict__ pa) {
  __shared__ unsigned hist[256];
  __shared__ unsigned long long bkey[512];
  __shared__ int bcount;
  __shared__ int boundary_bin, need_s;
  __shared__ unsigned char selflag[512];
  __shared__ float redM[8], redE[8], redA[8];
  __shared__ float posnum;

  const int t = threadIdx.x;
  const int row = blockIdx.x;  // b*512 + m
  const int m = row & (NM - 1);
  const bool self = (t == m);

  unsigned bits = threefry_bits((unsigned)row * 512u + (unsigned)t);
  unsigned u = bits >> 9;
  unsigned key = (u << 9) | (unsigned)(511 - t);
  int bin = (int)(u >> 15);

  if (t < 256) hist[t] = 0;
  if (t == 0) bcount = 0;
  selflag[t] = 0;
  __syncthreads();

  if (!self) atomicAdd(&hist[bin], 1u);
  __syncthreads();

  if (t < 64) {
    unsigned h0 = hist[4 * t + 0], h1 = hist[4 * t + 1];
    unsigned h2 = hist[4 * t + 2], h3 = hist[4 * t + 3];
    unsigned s = h0 + h1 + h2 + h3;
    unsigned suf = s;
#pragma unroll
    for (int off = 1; off < 64; off <<= 1) {
      unsigned o = __shfl_down(suf, off, 64);
      if (t + off < 64) suf += o;
    }
    unsigned a3 = suf - s;
    unsigned a2 = a3 + h3;
    unsigned a1 = a2 + h2;
    unsigned a0 = a1 + h1;
    if (a3 < NNEG && a3 + h3 >= NNEG) { boundary_bin = 4 * t + 3; need_s = NNEG - (int)a3; }
    if (a2 < NNEG && a2 + h2 >= NNEG) { boundary_bin = 4 * t + 2; need_s = NNEG - (int)a2; }
    if (a1 < NNEG && a1 + h1 >= NNEG) { boundary_bin = 4 * t + 1; need_s = NNEG - (int)a1; }
    if (a0 < NNEG && a0 + h0 >= NNEG) { boundary_bin = 4 * t + 0; need_s = NNEG - (int)a0; }
  }
  __syncthreads();

  const int bb = boundary_bin;
  if (!self) {
    if (bin > bb) selflag[t] = 1;
    else if (bin == bb) {
      int p = atomicAdd(&bcount, 1);
      bkey[p] = (((unsigned long long)key) << 1) | 1ull;
    }
  }
  __syncthreads();

  if (t == 0) {
    int cnt = bcount, need = need_s;
    for (int it = 0; it < need; ++it) {
      unsigned long long best = 0ull; int bi = 0;
      for (int q = 0; q < cnt; ++q)
        if (bkey[q] > best) { best = bkey[q]; bi = q; }
      bkey[bi] = 0ull;
      int tt = 511 - (int)((best >> 1) & 511ull);
      selflag[tt] = 1;
    }
  }
  __syncthreads();

  const float* Srow = S + (size_t)row * NM;
  const bool act = (selflag[t] != 0) || self;
  const float logitv = Srow[t];
  const int wid = t >> 6;

  float mv = act ? logitv : -3.4e38f;
#pragma unroll
  for (int off = 32; off > 0; off >>= 1) mv = fmaxf(mv, __shfl_xor(mv, off, 64));
  if ((t & 63) == 0) redM[wid] = mv;
  __syncthreads();
  float mx = redM[0];
#pragma unroll
  for (int q = 1; q < 8; ++q) mx = fmaxf(mx, redM[q]);

  float e = 0.f, a = 0.f;
  if (act) {
    e = __expf(logitv - mx);
    float th = 1.f - 2.f / (__expf(2.f * logitv) + 1.f); // robust tanh
    a = th * th;
  }
  if (self) posnum = e;

  float es = e, as = a;
#pragma unroll
  for (int off = 32; off > 0; off >>= 1) {
    es += __shfl_xor(es, off, 64);
    as += __shfl_xor(as, off, 64);
  }
  if ((t & 63) == 0) { redE[wid] = es; redA[wid] = as; }
  __syncthreads();

  if (t == 0) {
    float den = 0.f, aux = 0.f;
#pragma unroll
    for (int q = 0; q < 8; ++q) { den += redE[q]; aux += redA[q]; }
    pl[row] = posnum / den;
    pa[row] = aux;
  }
}

// ---------------- Kernel 4: deterministic final reduction ----------------
__global__ __launch_bounds__(1024) void k_red(const float* __restrict__ pl,
                                              const float* __restrict__ pa,
                                              float* __restrict__ out) {
  __shared__ float s1[1024], s2[1024];
  const int t = threadIdx.x;
  float a = 0.f, b = 0.f;
  for (int q = t; q < NB * NM; q += 1024) { a += pl[q]; b += pa[q]; }
  s1[t] = a; s2[t] = b;
  __syncthreads();
  for (int off = 512; off > 0; off >>= 1) {
    if (t < off) { s1[t] += s1[t + off]; s2[t] += s2[t + off]; }
    __syncthreads();
  }
  if (t == 0) { out[0] = s1[0]; out[1] = s2[0]; }
}

extern "C" void kernel_launch(void* const* d_in, const int* in_sizes, int n_in,
                              void* d_out, int out_size, void* d_ws, size_t ws_size,
                              hipStream_t stream) {
  const float* feat = (const float*)d_in[0];  // feat_proj [B,C,T]
  const void*  mask = d_in[1];                // mask [B,T] bool
  const float* ctx  = (const float*)d_in[2];  // context_output [B,C,T]
  float* out = (float*)d_out;

  char* ws = (char*)d_ws;
  int*   idxp = (int*)ws;                          // 16 KB
  int*   pos  = (int*)(ws + 16384);                // 32 KB
  char*  base = ws + 65536;
  float* MC = (float*)base;                        // 4 MB  [B,M,C]
  float* MF = (float*)(base + (4u << 20));         // 4 MB  [B,M,C]
  float* S  = (float*)(base + (8u << 20));         // 8 MB  [B,M,M]
  float* pl = (float*)(base + (16u << 20));        // 16 KB
  float* pa = pl + NB * NM;                        // 16 KB

  k_idx<<<1, 512, 0, stream>>>(mask, idxp, pos);

  dim3 gc(NT / 128, NC / 64, NB * 2); // (t-slabs, c-slabs, b*2+mat)
  k_compact<<<gc, 256, 0, stream>>>(ctx, feat, pos, MC, MF);

  dim3 g2(NM / 64, NM / 64, NB);
  k_gemm2<<<g2, 256, 0, stream>>>(MC, MF, S);

  k_loss<<<NB * NM, 512, 0, stream>>>(S, pl, pa);

  k_red<<<1, 1024, 0, stream>>>(pl, pa, out);
}

// Round 4
// 62.845 us; speedup vs baseline: 1.0815x; 1.0815x over previous
//
#include <hip/hip_runtime.h>
#include <stdint.h>

#define NB   8
#define NC   256
#define NT   1024
#define NM   512
#define NNEG 100

typedef unsigned short u16;
typedef __attribute__((ext_vector_type(8))) short bf16x8;
typedef __attribute__((ext_vector_type(4))) float f32x4;

// ---------------- Threefry-2x32-20 (JAX) ----------------
__device__ __forceinline__ unsigned rotl32(unsigned x, int d) {
  return (x << d) | (x >> (32 - d));
}

__device__ unsigned threefry_bits(unsigned i) {
  const unsigned half = 1048576u; // 2^20
  const bool lo = i < half;
  unsigned v0 = lo ? i : (i - half);
  unsigned v1 = lo ? (i + half) : i;
  const unsigned k0 = 0u, k1 = 42u;
  const unsigned k2 = k0 ^ k1 ^ 0x1BD11BDAu;
  v0 += k0; v1 += k1;
#define TF_R(r) { v0 += v1; v1 = rotl32(v1, r); v1 ^= v0; }
  TF_R(13) TF_R(15) TF_R(26) TF_R(6)
  v0 += k1; v1 += k2 + 1u;
  TF_R(17) TF_R(29) TF_R(16) TF_R(24)
  v0 += k2; v1 += k0 + 2u;
  TF_R(13) TF_R(15) TF_R(26) TF_R(6)
  v0 += k0; v1 += k1 + 3u;
  TF_R(17) TF_R(29) TF_R(16) TF_R(24)
  v0 += k1; v1 += k2 + 4u;
  TF_R(13) TF_R(15) TF_R(26) TF_R(6)
  v0 += k2; v1 += k0 + 5u;
#undef TF_R
  return lo ? v0 : v1;
}

// ---------------- Kernel 1: compact + bf16 hi/lo split ----------------
// Block = (t-slab of 128, b*2+mat). Recomputes the mask prefix for its row
// (cheap, removes the k_idx kernel + dependency), then LDS-transposes a
// [64c x 128t] chunk and writes masked columns as bf16 hi/lo planes [B,M,C].
__global__ __launch_bounds__(256) void k_compact(const float* __restrict__ ctx,
                                                 const float* __restrict__ feat,
                                                 const void* __restrict__ maskp,
                                                 u16* __restrict__ MCh, u16* __restrict__ MCl,
                                                 u16* __restrict__ MFh, u16* __restrict__ MFl) {
  __shared__ float lds[64][129];
  __shared__ int posl[128];
  __shared__ int wsum[4];
  __shared__ int det[3];
  const int tid = threadIdx.x;
  const int lane = tid & 63, wid = tid >> 6;
  const int t0 = blockIdx.x * 128;
  const int b = blockIdx.y >> 1, mat = blockIdx.y & 1;
  const unsigned char* mb = (const unsigned char*)maskp;

  if (tid < 3) det[tid] = 0;
  __syncthreads();
  { // storage-width detection over first 1024 elements (>=8KB in-bounds)
    int c1 = 0, c4 = 0, c8 = 0;
    for (int j = tid; j < 1024; j += 256) {
      c1 += (mb[j] != 0);
      c4 += (((const unsigned*)mb)[j] != 0u);
      c8 += (((const unsigned long long*)mb)[j] != 0ull);
    }
#pragma unroll
    for (int off = 32; off; off >>= 1) {
      c1 += __shfl_xor(c1, off, 64);
      c4 += __shfl_xor(c4, off, 64);
      c8 += __shfl_xor(c8, off, 64);
    }
    if (lane == 0) { atomicAdd(&det[0], c1); atomicAdd(&det[1], c4); atomicAdd(&det[2], c8); }
  }
  __syncthreads();
  const int stride = (det[1] == 512) ? 4 : ((det[0] == 512) ? 1 : ((det[2] == 512) ? 8 : 4));

  // full-row exclusive prefix for batch b (thread covers 4 consecutive t)
  int f4[4]; int s = 0;
#pragma unroll
  for (int j = 0; j < 4; ++j) {
    int tt = 4 * tid + j;
    size_t e = (size_t)b * NT + tt;
    int f;
    if (stride == 1)      f = (mb[e] != 0);
    else if (stride == 4) f = (((const unsigned*)mb)[e] != 0u);
    else                  f = (((const unsigned long long*)mb)[e] != 0ull);
    f4[j] = f; s += f;
  }
  int incl = s;
#pragma unroll
  for (int off = 1; off < 64; off <<= 1) {
    int o = __shfl_up(incl, off, 64);
    if (lane >= off) incl += o;
  }
  if (lane == 63) wsum[wid] = incl;
  __syncthreads();
  int wbase = 0;
#pragma unroll
  for (int w = 0; w < 4; ++w) if (w < wid) wbase += wsum[w];
  int excl = wbase + incl - s;
#pragma unroll
  for (int j = 0; j < 4; ++j) {
    int tt = 4 * tid + j;
    if (tt >= t0 && tt < t0 + 128) posl[tt - t0] = f4[j] ? excl : -1;
    excl += f4[j];
  }

  const float* src = (mat ? feat : ctx) + (size_t)b * NC * NT;
  u16* dh = (mat ? MFh : MCh) + (size_t)b * NM * NC;
  u16* dl = (mat ? MFl : MCl) + (size_t)b * NM * NC;

  const int c4i = tid >> 6, tl = tid & 63, tr = tid >> 6;
  for (int chunk = 0; chunk < 4; ++chunk) {
    int c0 = chunk * 64;
    __syncthreads();
    for (int ci = 0; ci < 16; ++ci) {
      int cc = c4i * 16 + ci;
#pragma unroll
      for (int tj = 0; tj < 2; ++tj) {
        int tt = tl + 64 * tj;
        lds[cc][tt] = src[(size_t)(c0 + cc) * NT + t0 + tt];
      }
    }
    __syncthreads();
    for (int tt = tr; tt < 128; tt += 4) {
      int p = posl[tt];
      if (p >= 0) {
        float x = lds[tl][tt];
        unsigned xb = __float_as_uint(x);
        u16 hi = (u16)(xb >> 16);                       // truncate -> exact hi
        float hif = __uint_as_float((unsigned)hi << 16);
        float rlo = x - hif;                            // exact remainder
        u16 lo = (u16)(__float_as_uint(rlo) >> 16);
        dh[(size_t)p * NC + c0 + tl] = hi;
        dl[(size_t)p * NC + c0 + tl] = lo;
      }
    }
  }
}

// ---------------- Kernel 2: split-bf16 MFMA GEMM ----------------
// S[b][m][j] = sum_c MC[m][c]*MF[j][c] via Ah*Bh + Ah*Bl + Al*Bh.
// 128x64 tile / 256 thr (4 waves, 2x2), wave-tile 64x32, K-step 32,
// double-buffered LDS (pitch 80B -> conflict-free b128 fragment reads).
// A/B fragments use the SAME (lane-group,slot)->k map, so the result is
// invariant to the HW k-permutation; C/D layout per guide (m89-verified).
__global__ __launch_bounds__(256) void k_gemm(const u16* __restrict__ MCh, const u16* __restrict__ MCl,
                                              const u16* __restrict__ MFh, const u16* __restrict__ MFl,
                                              float* __restrict__ S) {
  // ushort units: per buffer: AH@0(128x40), AL@5120, BH@10240(64x40), BL@12800; buf stride 15360
  __shared__ u16 smem[30720];
  const int tid = threadIdx.x;
  const int b = blockIdx.z;
  const int m0 = blockIdx.y * 128;
  const int j0 = blockIdx.x * 64;
  const int wave = tid >> 6, lane = tid & 63;
  const int wm = wave >> 1, wn = wave & 1;
  const int r = lane & 15, g = lane >> 4;

  // staging mapping (stride-20-word rows tile all 32 banks conflict-free)
  const int arow = tid & 127, ah2 = tid >> 7;
  const int brow = tid & 63,  bh2 = (tid >> 6) & 1, bmat = tid >> 7;

  const u16* Agh = MCh + (size_t)(b * NM + m0 + arow) * NC;
  const u16* Agl = MCl + (size_t)(b * NM + m0 + arow) * NC;
  const u16* Bg  = (bmat ? MFl : MFh) + (size_t)(b * NM + j0 + brow) * NC;

  uint4 rA0, rA1, rL0, rL1, rB0, rB1;
  auto load_regs = [&](int c0) {
    const uint4* p;
    p = (const uint4*)(Agh + c0 + 16 * ah2); rA0 = p[0]; rA1 = p[1];
    p = (const uint4*)(Agl + c0 + 16 * ah2); rL0 = p[0]; rL1 = p[1];
    p = (const uint4*)(Bg  + c0 + 16 * bh2); rB0 = p[0]; rB1 = p[1];
  };
  auto write_lds = [&](int buf) {
    u16* base = smem + buf * 15360;
    u16* d;
    d = base + arow * 40 + 16 * ah2;
    *(uint4*)d = rA0; *(uint4*)(d + 8) = rA1;
    d = base + 5120 + arow * 40 + 16 * ah2;
    *(uint4*)d = rL0; *(uint4*)(d + 8) = rL1;
    d = base + 10240 + bmat * 2560 + brow * 40 + 16 * bh2;
    *(uint4*)d = rB0; *(uint4*)(d + 8) = rB1;
  };

  f32x4 z = {0.f, 0.f, 0.f, 0.f};
  f32x4 acc[4][2];
#pragma unroll
  for (int m = 0; m < 4; ++m) { acc[m][0] = z; acc[m][1] = z; }

  const int aro = (wm * 64 + r) * 40 + g * 8;  // + m*640
  const int bro = (wn * 32 + r) * 40 + g * 8;  // + n*640

  load_regs(0);
  write_lds(0);
  __syncthreads();

  for (int ks = 0; ks < 8; ++ks) {
    const int cur = ks & 1;
    if (ks < 7) load_regs((ks + 1) * 32);
    {
      const u16* base = smem + cur * 15360;
      bf16x8 ah[4], al[4];
#pragma unroll
      for (int m = 0; m < 4; ++m) {
        ah[m] = *(const bf16x8*)(base + aro + m * 640);
        al[m] = *(const bf16x8*)(base + 5120 + aro + m * 640);
      }
#pragma unroll
      for (int n = 0; n < 2; ++n) {
        bf16x8 bh = *(const bf16x8*)(base + 10240 + bro + n * 640);
        bf16x8 bl = *(const bf16x8*)(base + 12800 + bro + n * 640);
#pragma unroll
        for (int m = 0; m < 4; ++m) {
          acc[m][n] = __builtin_amdgcn_mfma_f32_16x16x32_bf16(ah[m], bh, acc[m][n], 0, 0, 0);
          acc[m][n] = __builtin_amdgcn_mfma_f32_16x16x32_bf16(ah[m], bl, acc[m][n], 0, 0, 0);
          acc[m][n] = __builtin_amdgcn_mfma_f32_16x16x32_bf16(al[m], bh, acc[m][n], 0, 0, 0);
        }
      }
    }
    if (ks < 7) write_lds(cur ^ 1);
    __syncthreads();
  }

  float* Sb = S + (size_t)b * NM * NM;
#pragma unroll
  for (int m = 0; m < 4; ++m)
#pragma unroll
    for (int n = 0; n < 2; ++n)
#pragma unroll
      for (int q = 0; q < 4; ++q) {
        int row = m0 + wm * 64 + m * 16 + g * 4 + q;
        int col = j0 + wn * 32 + n * 16 + r;
        Sb[(size_t)row * NM + col] = acc[m][n][q];
      }
}

// ---------------- Kernel 3: histogram top-100 + parallel loss ----------------
__global__ __launch_bounds__(512) void k_loss(const float* __restrict__ S,
                                              float* __restrict__ pl,
                                              float* __restrict__ pa) {
  __shared__ unsigned hist[256];
  __shared__ unsigned long long bkey[512];
  __shared__ int bcount;
  __shared__ int boundary_bin, need_s;
  __shared__ unsigned char selflag[512];
  __shared__ float redM[8], redE[8], redA[8];
  __shared__ float posnum;

  const int t = threadIdx.x;
  const int row = blockIdx.x;  // b*512 + m
  const int m = row & (NM - 1);
  const bool self = (t == m);

  unsigned bits = threefry_bits((unsigned)row * 512u + (unsigned)t);
  unsigned u = bits >> 9;
  unsigned key = (u << 9) | (unsigned)(511 - t);
  int bin = (int)(u >> 15);

  if (t < 256) hist[t] = 0;
  if (t == 0) bcount = 0;
  selflag[t] = 0;
  __syncthreads();

  if (!self) atomicAdd(&hist[bin], 1u);
  __syncthreads();

  if (t < 64) {
    unsigned h0 = hist[4 * t + 0], h1 = hist[4 * t + 1];
    unsigned h2 = hist[4 * t + 2], h3 = hist[4 * t + 3];
    unsigned s = h0 + h1 + h2 + h3;
    unsigned suf = s;
#pragma unroll
    for (int off = 1; off < 64; off <<= 1) {
      unsigned o = __shfl_down(suf, off, 64);
      if (t + off < 64) suf += o;
    }
    unsigned a3 = suf - s;
    unsigned a2 = a3 + h3;
    unsigned a1 = a2 + h2;
    unsigned a0 = a1 + h1;
    if (a3 < NNEG && a3 + h3 >= NNEG) { boundary_bin = 4 * t + 3; need_s = NNEG - (int)a3; }
    if (a2 < NNEG && a2 + h2 >= NNEG) { boundary_bin = 4 * t + 2; need_s = NNEG - (int)a2; }
    if (a1 < NNEG && a1 + h1 >= NNEG) { boundary_bin = 4 * t + 1; need_s = NNEG - (int)a1; }
    if (a0 < NNEG && a0 + h0 >= NNEG) { boundary_bin = 4 * t + 0; need_s = NNEG - (int)a0; }
  }
  __syncthreads();

  const int bb = boundary_bin;
  if (!self) {
    if (bin > bb) selflag[t] = 1;
    else if (bin == bb) {
      int p = atomicAdd(&bcount, 1);
      bkey[p] = (((unsigned long long)key) << 1) | 1ull;
    }
  }
  __syncthreads();

  if (t == 0) {
    int cnt = bcount, need = need_s;
    for (int it = 0; it < need; ++it) {
      unsigned long long best = 0ull; int bi = 0;
      for (int q = 0; q < cnt; ++q)
        if (bkey[q] > best) { best = bkey[q]; bi = q; }
      bkey[bi] = 0ull;
      int tt = 511 - (int)((best >> 1) & 511ull);
      selflag[tt] = 1;
    }
  }
  __syncthreads();

  const float* Srow = S + (size_t)row * NM;
  const bool act = (selflag[t] != 0) || self;
  const float logitv = Srow[t];
  const int wid = t >> 6;

  float mv = act ? logitv : -3.4e38f;
#pragma unroll
  for (int off = 32; off > 0; off >>= 1) mv = fmaxf(mv, __shfl_xor(mv, off, 64));
  if ((t & 63) == 0) redM[wid] = mv;
  __syncthreads();
  float mx = redM[0];
#pragma unroll
  for (int q = 1; q < 8; ++q) mx = fmaxf(mx, redM[q]);

  float e = 0.f, a = 0.f;
  if (act) {
    e = __expf(logitv - mx);
    float th = 1.f - 2.f / (__expf(2.f * logitv) + 1.f);
    a = th * th;
  }
  if (self) posnum = e;

  float es = e, as = a;
#pragma unroll
  for (int off = 32; off > 0; off >>= 1) {
    es += __shfl_xor(es, off, 64);
    as += __shfl_xor(as, off, 64);
  }
  if ((t & 63) == 0) { redE[wid] = es; redA[wid] = as; }
  __syncthreads();

  if (t == 0) {
    float den = 0.f, aux = 0.f;
#pragma unroll
    for (int q = 0; q < 8; ++q) { den += redE[q]; aux += redA[q]; }
    pl[row] = posnum / den;
    pa[row] = aux;
  }
}

// ---------------- Kernel 4: deterministic final reduction ----------------
__global__ __launch_bounds__(1024) void k_red(const float* __restrict__ pl,
                                              const float* __restrict__ pa,
                                              float* __restrict__ out) {
  __shared__ float s1[1024], s2[1024];
  const int t = threadIdx.x;
  float a = 0.f, b = 0.f;
  for (int q = t; q < NB * NM; q += 1024) { a += pl[q]; b += pa[q]; }
  s1[t] = a; s2[t] = b;
  __syncthreads();
  for (int off = 512; off > 0; off >>= 1) {
    if (t < off) { s1[t] += s1[t + off]; s2[t] += s2[t + off]; }
    __syncthreads();
  }
  if (t == 0) { out[0] = s1[0]; out[1] = s2[0]; }
}

extern "C" void kernel_launch(void* const* d_in, const int* in_sizes, int n_in,
                              void* d_out, int out_size, void* d_ws, size_t ws_size,
                              hipStream_t stream) {
  const float* feat = (const float*)d_in[0];  // feat_proj [B,C,T]
  const void*  mask = d_in[1];                // mask [B,T] bool
  const float* ctx  = (const float*)d_in[2];  // context_output [B,C,T]
  float* out = (float*)d_out;

  char* ws = (char*)d_ws;
  u16*   MCh = (u16*)ws;                           // 2 MB  [B,M,C] bf16 hi (ctx)
  u16*   MCl = (u16*)(ws + (2u << 20));            // 2 MB  lo
  u16*   MFh = (u16*)(ws + (4u << 20));            // 2 MB  (feat)
  u16*   MFl = (u16*)(ws + (6u << 20));            // 2 MB
  float* S   = (float*)(ws + (8u << 20));          // 8 MB  [B,M,M] f32
  float* pl  = (float*)(ws + (16u << 20));         // 16 KB
  float* pa  = pl + NB * NM;                       // 16 KB

  dim3 gc(NT / 128, NB * 2);  // (t-slab, b*2+mat)
  k_compact<<<gc, 256, 0, stream>>>(ctx, feat, mask, MCh, MCl, MFh, MFl);

  dim3 g2(NM / 64, NM / 128, NB);  // 8 x 4 x 8 = 256 blocks
  k_gemm<<<g2, 256, 0, stream>>>(MCh, MCl, MFh, MFl, S);

  k_loss<<<NB * NM, 512, 0, stream>>>(S, pl, pa);

  k_red<<<1, 1024, 0, stream>>>(pl, pa, out);
}